// Round 6
// baseline (490.007 us; speedup 1.0000x reference)
//
#include <hip/hip_runtime.h>
#include <math.h>

constexpr int Bb   = 2;
constexpr int Nn   = 2048;
constexpr int Dd   = 1024;
constexpr int Hh   = 16;
constexpr int HD   = 64;
constexpr int KVW  = 2*Dd;       // kv row width; cols [0,1024)=qk, [1024,2048)=v
constexpr int KSL  = 512;        // PM slab width: keeps U+PM working set < L3 (256MB)
constexpr float SHIFT = 20.f;    // constant softmax shift: exact math, keeps exp in range

typedef short bf16x8 __attribute__((ext_vector_type(8)));
typedef float f32x4  __attribute__((ext_vector_type(4)));

__device__ inline float bf2f(unsigned short u){
  union { unsigned int i; float f; } x; x.i = ((unsigned int)u) << 16; return x.f;
}
__device__ inline unsigned short f2bf(float f){
  union { float f; unsigned int i; } x; x.f = f;
  unsigned int r = x.i + 0x7fffu + ((x.i >> 16) & 1u);
  return (unsigned short)(r >> 16);
}
__device__ inline void storeC(float* p, float v, int accum){ if (accum) *p += v; else *p = v; }
__device__ inline void storeC(unsigned short* p, float v, int){ *p = f2bf(v); }

// ---------------- LayerNorm: one block per row, bf16 out ----------------
__global__ __launch_bounds__(256) void ln_kernel(const float* __restrict__ x,
    const float* __restrict__ g, const float* __restrict__ bta, unsigned short* __restrict__ h){
  int row = blockIdx.x, tid = threadIdx.x;
  const float4* x4 = (const float4*)(x + (size_t)row*Dd);
  float4 v = x4[tid];
  float s  = v.x+v.y+v.z+v.w;
  float s2 = v.x*v.x+v.y*v.y+v.z*v.z+v.w*v.w;
#pragma unroll
  for (int off=32; off>0; off>>=1){ s += __shfl_down(s,off); s2 += __shfl_down(s2,off); }
  __shared__ float red[8];
  if ((tid&63)==0){ red[tid>>6]=s; red[4+(tid>>6)]=s2; }
  __syncthreads();
  s  = red[0]+red[1]+red[2]+red[3];
  s2 = red[4]+red[5]+red[6]+red[7];
  float mu = s*(1.f/Dd);
  float rs = rsqrtf(fmaxf(s2*(1.f/Dd)-mu*mu,0.f)+1e-5f);
  float4 gv=((const float4*)g)[tid], bv=((const float4*)bta)[tid];
  ushort4 o;
  o.x=f2bf((v.x-mu)*rs*gv.x+bv.x); o.y=f2bf((v.y-mu)*rs*gv.y+bv.y);
  o.z=f2bf((v.z-mu)*rs*gv.z+bv.z); o.w=f2bf((v.w-mu)*rs*gv.w+bv.w);
  ((ushort4*)(h+(size_t)row*Dd))[tid]=o;
}

// ---------------- fp32 -> bf16 transposing weight prep: out[c][r] = in[r][c] ----
__global__ __launch_bounds__(256) void wT_kernel(const float* __restrict__ in,
    unsigned short* __restrict__ out, int R, int Cc){
  __shared__ float t[32][33];
  int c0 = blockIdx.x*32, r0 = blockIdx.y*32;
  int tx = threadIdx.x&31, ty = threadIdx.x>>5;   // 32 x 8
#pragma unroll
  for (int k=0;k<4;k++)
    t[ty+8*k][tx] = in[(size_t)(r0+ty+8*k)*Cc + c0+tx];
  __syncthreads();
#pragma unroll
  for (int k=0;k<4;k++)
    out[(size_t)(c0+ty+8*k)*R + r0+tx] = f2bf(t[tx][ty+8*k]);
}

// ---------------- bf16 V transpose: vT[b][d][k] = kvb[b][k][Dd+d] ----------------
__global__ __launch_bounds__(256) void vT_kernel(const unsigned short* __restrict__ kvb,
    unsigned short* __restrict__ vT){
  __shared__ unsigned short t[32][33];
  int b = blockIdx.z;
  int d0 = blockIdx.x*32, k0 = blockIdx.y*32;
  const unsigned short* in = kvb + (size_t)b*Nn*KVW + Dd;
  unsigned short* out = vT + (size_t)b*Dd*Nn;
  int tx = threadIdx.x&31, ty = threadIdx.x>>5;
#pragma unroll
  for (int k=0;k<4;k++)
    t[ty+8*k][tx] = in[(size_t)(k0+ty+8*k)*KVW + d0+tx];
  __syncthreads();
#pragma unroll
  for (int k=0;k<4;k++)
    out[(size_t)(d0+ty+8*k)*Nn + k0+tx] = t[tx][ty+8*k];
}

// ---------------- fp32 -> bf16 elementwise ----------------
__global__ __launch_bounds__(256) void cvt_kernel(const float* __restrict__ in,
    unsigned short* __restrict__ out){
  int i = blockIdx.x*256 + threadIdx.x;
  float4 v = ((const float4*)in)[i];
  ushort4 o; o.x=f2bf(v.x); o.y=f2bf(v.y); o.z=f2bf(v.z); o.w=f2bf(v.w);
  ((ushort4*)out)[i] = o;
}

// ---------------- zero the l-sums (ws is poisoned each call) ----------------
__global__ __launch_bounds__(256) void zero_kernel(float* __restrict__ p){
  ((float4*)p)[blockIdx.x*256 + threadIdx.x] = float4{0.f,0.f,0.f,0.f};
}

// ---------------- Generic batched bf16 MFMA GEMM: C = A @ Bt^T ----------------
// BM=128 x BN x BK=32, 4 waves, padded RS=40 rows, reg prefetch. (proven r4/r5)
template <int BN, typename CT>
__global__ __launch_bounds__(256) void mgemm(
    const unsigned short* __restrict__ A, const unsigned short* __restrict__ Bt,
    CT* __restrict__ C, int K, int lda, int ldb, int ldc,
    long sAz, long sBz, long sCz, int accum){
  constexpr int BM = 128, BK = 32;
  constexpr int RS = 40;
  constexpr int WC = (BN==128)?2:1;
  constexpr int WR = 4/WC;
  constexpr int FM = BM/(WR*16);
  constexpr int FN = BN/(WC*16);
  __shared__ __align__(16) short As[BM*RS];
  __shared__ __align__(16) short Bs[BN*RS];
  int tid = threadIdx.x;
  long z = blockIdx.z;
  const unsigned short* Ab = A + z*sAz + (size_t)blockIdx.y*BM*lda;
  const unsigned short* Bb = Bt + z*sBz + (size_t)blockIdx.x*BN*ldb;
  CT* Cb = C + z*sCz + (size_t)blockIdx.y*BM*ldc + (size_t)blockIdx.x*BN;
  int wid = tid>>6, lane = tid&63;
  int wr = (WC==2)?(wid>>1):wid;
  int wc = (WC==2)?(wid&1):0;
  int r0 = tid>>2, s0 = tid&3;
  f32x4 acc[FM][FN] = {};
  int nk = K/BK;
  uint4 a0, a1, b0, b1;
  a0 = *(const uint4*)(Ab + (size_t)r0*lda + s0*8);
  a1 = *(const uint4*)(Ab + (size_t)(r0+64)*lda + s0*8);
  b0 = *(const uint4*)(Bb + (size_t)r0*ldb + s0*8);
  if constexpr (BN==128) b1 = *(const uint4*)(Bb + (size_t)(r0+64)*ldb + s0*8);
  *(uint4*)&As[r0*RS + s0*8]      = a0;
  *(uint4*)&As[(r0+64)*RS + s0*8] = a1;
  *(uint4*)&Bs[r0*RS + s0*8]      = b0;
  if constexpr (BN==128) *(uint4*)&Bs[(r0+64)*RS + s0*8] = b1;
  __syncthreads();
  for (int t=0; t<nk; t++){
    if (t+1 < nk){
      int k0 = (t+1)*BK;
      a0 = *(const uint4*)(Ab + (size_t)r0*lda + k0 + s0*8);
      a1 = *(const uint4*)(Ab + (size_t)(r0+64)*lda + k0 + s0*8);
      b0 = *(const uint4*)(Bb + (size_t)r0*ldb + k0 + s0*8);
      if constexpr (BN==128) b1 = *(const uint4*)(Bb + (size_t)(r0+64)*ldb + k0 + s0*8);
    }
    bf16x8 af[FM], bfr[FN];
#pragma unroll
    for (int m=0;m<FM;m++){
      int row = wr*(FM*16) + m*16 + (lane&15);
      af[m] = *(const bf16x8*)&As[row*RS + (lane>>4)*8];
    }
#pragma unroll
    for (int n=0;n<FN;n++){
      int col = wc*(FN*16) + n*16 + (lane&15);
      bfr[n] = *(const bf16x8*)&Bs[col*RS + (lane>>4)*8];
    }
#pragma unroll
    for (int m=0;m<FM;m++)
#pragma unroll
      for (int n=0;n<FN;n++)
        acc[m][n] = __builtin_amdgcn_mfma_f32_16x16x32_bf16(af[m], bfr[n], acc[m][n], 0, 0, 0);
    if (t+1 < nk){
      __syncthreads();
      *(uint4*)&As[r0*RS + s0*8]      = a0;
      *(uint4*)&As[(r0+64)*RS + s0*8] = a1;
      *(uint4*)&Bs[r0*RS + s0*8]      = b0;
      if constexpr (BN==128) *(uint4*)&Bs[(r0+64)*RS + s0*8] = b1;
      __syncthreads();
    }
  }
#pragma unroll
  for (int m=0;m<FM;m++){
    int row = wr*(FM*16) + m*16 + (lane>>4)*4;
#pragma unroll
    for (int n=0;n<FN;n++){
      int col = wc*(FN*16) + n*16 + (lane&15);
#pragma unroll
      for (int rg=0;rg<4;rg++)
        storeC(Cb + (size_t)(row+rg)*ldc + col, acc[m][n][rg], accum);
    }
  }
}

// ------ QK^T + exp epilogue + denominator atomics: U[h][q][k] = bf16(exp(S-SHIFT)),
// ------ lsum[h][q] += row-partials. (proven r5)
__global__ __launch_bounds__(256) void sqexp_kernel(
    const unsigned short* __restrict__ A,   // kvb_b (q rows), +h*64 per z
    const unsigned short* __restrict__ Bt,  // kvb_b (k rows), +h*64 per z
    unsigned short* __restrict__ U,         // [h][Nn][Nn]
    float* __restrict__ lsum){              // [h][Nn], pre-zeroed
  constexpr int BM = 128, BN = 128, BK = 32, RS = 40;
  constexpr int FM = 4, FN = 4;
  __shared__ __align__(16) short As[BM*RS];
  __shared__ __align__(16) short Bs[BN*RS];
  int tid = threadIdx.x;
  long z = blockIdx.z;                      // head
  const unsigned short* Ab = A + z*HD + (size_t)blockIdx.y*BM*KVW;
  const unsigned short* Bb = Bt + z*HD + (size_t)blockIdx.x*BN*KVW;
  unsigned short* Ub = U + z*(size_t)Nn*Nn + (size_t)blockIdx.y*BM*Nn + (size_t)blockIdx.x*BN;
  float* lrow = lsum + z*Nn + blockIdx.y*BM;
  int wid = tid>>6, lane = tid&63;
  int wr = wid>>1, wc = wid&1;
  int r0 = tid>>2, s0 = tid&3;
  f32x4 acc[FM][FN] = {};
  uint4 a0, a1, b0, b1;
  a0 = *(const uint4*)(Ab + (size_t)r0*KVW + s0*8);
  a1 = *(const uint4*)(Ab + (size_t)(r0+64)*KVW + s0*8);
  b0 = *(const uint4*)(Bb + (size_t)r0*KVW + s0*8);
  b1 = *(const uint4*)(Bb + (size_t)(r0+64)*KVW + s0*8);
  *(uint4*)&As[r0*RS + s0*8]      = a0;
  *(uint4*)&As[(r0+64)*RS + s0*8] = a1;
  *(uint4*)&Bs[r0*RS + s0*8]      = b0;
  *(uint4*)&Bs[(r0+64)*RS + s0*8] = b1;
  __syncthreads();
  for (int t=0; t<HD/BK; t++){
    if (t == 0){
      a0 = *(const uint4*)(Ab + (size_t)r0*KVW + BK + s0*8);
      a1 = *(const uint4*)(Ab + (size_t)(r0+64)*KVW + BK + s0*8);
      b0 = *(const uint4*)(Bb + (size_t)r0*KVW + BK + s0*8);
      b1 = *(const uint4*)(Bb + (size_t)(r0+64)*KVW + BK + s0*8);
    }
    bf16x8 af[FM], bfr[FN];
#pragma unroll
    for (int m=0;m<FM;m++)
      af[m] = *(const bf16x8*)&As[(wr*64 + m*16 + (lane&15))*RS + (lane>>4)*8];
#pragma unroll
    for (int n=0;n<FN;n++)
      bfr[n] = *(const bf16x8*)&Bs[(wc*64 + n*16 + (lane&15))*RS + (lane>>4)*8];
#pragma unroll
    for (int m=0;m<FM;m++)
#pragma unroll
      for (int n=0;n<FN;n++)
        acc[m][n] = __builtin_amdgcn_mfma_f32_16x16x32_bf16(af[m], bfr[n], acc[m][n], 0, 0, 0);
    if (t == 0){
      __syncthreads();
      *(uint4*)&As[r0*RS + s0*8]      = a0;
      *(uint4*)&As[(r0+64)*RS + s0*8] = a1;
      *(uint4*)&Bs[r0*RS + s0*8]      = b0;
      *(uint4*)&Bs[(r0+64)*RS + s0*8] = b1;
      __syncthreads();
    }
  }
  float part[FM][4];
#pragma unroll
  for (int m=0;m<FM;m++)
#pragma unroll
    for (int rg=0;rg<4;rg++) part[m][rg] = 0.f;
#pragma unroll
  for (int m=0;m<FM;m++){
    int row = wr*64 + m*16 + (lane>>4)*4;
#pragma unroll
    for (int n=0;n<FN;n++){
      int col = wc*64 + n*16 + (lane&15);
#pragma unroll
      for (int rg=0;rg<4;rg++){
        float e = __expf(acc[m][n][rg] - SHIFT);
        Ub[(size_t)(row+rg)*Nn + col] = f2bf(e);
        part[m][rg] += e;
      }
    }
  }
#pragma unroll
  for (int m=0;m<FM;m++)
#pragma unroll
    for (int rg=0;rg<4;rg++){
      float s = part[m][rg];
#pragma unroll
      for (int off=1; off<16; off<<=1) s += __shfl_xor(s, off);
      if ((lane&15)==0)
        atomicAdd(&lrow[wr*64 + m*16 + (lane>>4)*4 + rg], s);
    }
}

// ------ slab mix: PM[g][q][0..KSL) = bf16( sum_h Wx[g,h] * U[h][q][k0+kk] / l[h][q] )
// grid (Nn/2); block: 2 q-rows x 512 k, 4 elems/thread; pure streaming.
__global__ __launch_bounds__(256) void mix2s_kernel(
    const unsigned short* __restrict__ U, const float* __restrict__ Wx,
    const float* __restrict__ lsum, unsigned short* __restrict__ PM, int k0){
  int tid = threadIdx.x;
  int qr = tid>>7;                         // 0..1
  int q  = blockIdx.x*2 + qr;
  int kk = (tid&127)*4;                    // 0..508
  __shared__ float Wl[256];
  __shared__ float rl[2][16];
  Wl[tid] = Wx[tid];
  if (tid < 32) rl[tid>>4][tid&15] = 1.f/lsum[(size_t)(tid&15)*Nn + blockIdx.x*2 + (tid>>4)];
  __syncthreads();
  int ks = k0 + kk;
  float pm[16][4] = {};
#pragma unroll
  for (int h=0;h<16;h++){
    ushort4 u4 = *(const ushort4*)&U[((size_t)h*Nn+q)*Nn + ks];
    float r = rl[qr][h];
    float f0=bf2f(u4.x)*r, f1=bf2f(u4.y)*r, f2=bf2f(u4.z)*r, f3=bf2f(u4.w)*r;
#pragma unroll
    for (int g=0;g<16;g++){
      float w = Wl[g*16+h];
      pm[g][0]+=w*f0; pm[g][1]+=w*f1; pm[g][2]+=w*f2; pm[g][3]+=w*f3;
    }
  }
#pragma unroll
  for (int g=0;g<16;g++){
    ushort4 o;
    o.x=f2bf(pm[g][0]); o.y=f2bf(pm[g][1]); o.z=f2bf(pm[g][2]); o.w=f2bf(pm[g][3]);
    *(ushort4*)&PM[((size_t)g*Nn+q)*KSL + kk] = o;
  }
}

extern "C" void kernel_launch(void* const* d_in, const int* in_sizes, int n_in,
                              void* d_out, int out_size, void* d_ws, size_t ws_size,
                              hipStream_t stream){
  (void)in_sizes; (void)n_in; (void)out_size; (void)ws_size;
  const float* x    = (const float*)d_in[0];
  const float* lng  = (const float*)d_in[1];
  const float* lnb  = (const float*)d_in[2];
  const float* Wkv  = (const float*)d_in[3];
  const float* Wx   = (const float*)d_in[4];
  // d_in[5] = W_xa: dead code in reference (its output _o2 is discarded)
  const float* Wout = (const float*)d_in[6];
  float* out = (float*)d_out;

  char* p = (char*)d_ws;
  unsigned short* h_b   = (unsigned short*)p;   // 8 MB; dead after kvproj,
  float*          o1    = (float*)p;            //   reused as per-batch fp32 o1 accumulator
  p += (size_t)Bb*Nn*Dd*2;
  unsigned short* kvb   = (unsigned short*)p; p += (size_t)Bb*Nn*KVW*2;  // 16 MB
  unsigned short* WkvT  = (unsigned short*)p; p += (size_t)KVW*Dd*2;     // 4 MB
  unsigned short* WoutT = (unsigned short*)p; p += (size_t)Dd*Dd*2;      // 2 MB
  unsigned short* vTb   = (unsigned short*)p; p += (size_t)Bb*Dd*Nn*2;   // 8 MB
  unsigned short* o1b   = (unsigned short*)p; p += (size_t)Bb*Nn*Dd*2;   // 8 MB
  float*          lb    = (float*)p;          p += (size_t)Bb*Hh*Nn*4;   // 256 KB
  unsigned short* U     = (unsigned short*)p; p += (size_t)Hh*Nn*Nn*2;   // 134 MB
  unsigned short* PM    = (unsigned short*)p;                            // 33.5 MB slab

  // weight prep + LN + projections
  wT_kernel<<<dim3(KVW/32, Dd/32), 256, 0, stream>>>(Wkv, WkvT, Dd, KVW);
  wT_kernel<<<dim3(Dd/32, Dd/32), 256, 0, stream>>>(Wout, WoutT, Dd, Dd);
  ln_kernel<<<Bb*Nn, 256, 0, stream>>>(x, lng, lnb, h_b);
  mgemm<128, unsigned short><<<dim3(KVW/128, (Bb*Nn)/128, 1), 256, 0, stream>>>(
      h_b, WkvT, kvb, Dd, Dd, Dd, KVW, 0, 0, 0, 0);
  vT_kernel<<<dim3(Dd/32, Nn/32, Bb), 256, 0, stream>>>(kvb, vTb);
  zero_kernel<<<(Bb*Hh*Nn)/1024, 256, 0, stream>>>(lb);

  for (int b=0;b<Bb;b++){
    const unsigned short* kvb_b = kvb + (size_t)b*Nn*KVW;
    float* lb_b = lb + (size_t)b*Hh*Nn;
    // U = exp(QK^T - SHIFT) bf16 full-K; l-sums via epilogue atomics
    sqexp_kernel<<<dim3(Nn/128, Nn/128, Hh), 256, 0, stream>>>(kvb_b, kvb_b, U, lb_b);
    // slabbed mix+PV: PM slab (33.5MB) written then read immediately -> L3-resident
    for (int k0=0;k0<Nn;k0+=KSL){
      mix2s_kernel<<<Nn/2, 256, 0, stream>>>(U, Wx, lb_b, PM, k0);
      mgemm<64, float><<<dim3(1, Nn/128, Hh), 256, 0, stream>>>(
          PM, vTb + (size_t)b*Dd*Nn + k0, o1,
          KSL, KSL, Nn, Dd, (long)Nn*KSL, (long)64*Nn, 64, k0>0);
    }
    cvt_kernel<<<(Nn*Dd)/1024, 256, 0, stream>>>(o1, o1b + (size_t)b*Nn*Dd);
  }
  // out = o1 @ W_out (fp32 out)
  mgemm<128, float><<<dim3(Dd/128, (Bb*Nn)/128, 1), 256, 0, stream>>>(
      o1b, WoutT, out, Dd, Dd, Dd, Dd, 0, 0, 0, 0);
}

// Round 8
// 408.658 us; speedup vs baseline: 1.1991x; 1.1991x over previous
//
#include <hip/hip_runtime.h>
#include <math.h>

constexpr int Bb   = 2;
constexpr int Nn   = 2048;
constexpr int Dd   = 1024;
constexpr int Hh   = 16;
constexpr int HD   = 64;
constexpr int KVW  = 2*Dd;       // kv row width; cols [0,1024)=qk, [1024,2048)=v
constexpr float SHIFT = 20.f;    // constant softmax shift: exact math, keeps exp in range

typedef short bf16x8 __attribute__((ext_vector_type(8)));
typedef float f32x4  __attribute__((ext_vector_type(4)));

__device__ inline float bf2f(unsigned short u){
  union { unsigned int i; float f; } x; x.i = ((unsigned int)u) << 16; return x.f;
}
__device__ inline unsigned short f2bf(float f){
  union { float f; unsigned int i; } x; x.f = f;
  unsigned int r = x.i + 0x7fffu + ((x.i >> 16) & 1u);
  return (unsigned short)(r >> 16);
}
__device__ inline void storeC(float* p, float v, int accum){ if (accum) *p += v; else *p = v; }
__device__ inline void storeC(unsigned short* p, float v, int){ *p = f2bf(v); }

// ---------------- LayerNorm: one block per row, bf16 out ----------------
__global__ __launch_bounds__(256) void ln_kernel(const float* __restrict__ x,
    const float* __restrict__ g, const float* __restrict__ bta, unsigned short* __restrict__ h){
  int row = blockIdx.x, tid = threadIdx.x;
  const float4* x4 = (const float4*)(x + (size_t)row*Dd);
  float4 v = x4[tid];
  float s  = v.x+v.y+v.z+v.w;
  float s2 = v.x*v.x+v.y*v.y+v.z*v.z+v.w*v.w;
#pragma unroll
  for (int off=32; off>0; off>>=1){ s += __shfl_down(s,off); s2 += __shfl_down(s2,off); }
  __shared__ float red[8];
  if ((tid&63)==0){ red[tid>>6]=s; red[4+(tid>>6)]=s2; }
  __syncthreads();
  s  = red[0]+red[1]+red[2]+red[3];
  s2 = red[4]+red[5]+red[6]+red[7];
  float mu = s*(1.f/Dd);
  float rs = rsqrtf(fmaxf(s2*(1.f/Dd)-mu*mu,0.f)+1e-5f);
  float4 gv=((const float4*)g)[tid], bv=((const float4*)bta)[tid];
  ushort4 o;
  o.x=f2bf((v.x-mu)*rs*gv.x+bv.x); o.y=f2bf((v.y-mu)*rs*gv.y+bv.y);
  o.z=f2bf((v.z-mu)*rs*gv.z+bv.z); o.w=f2bf((v.w-mu)*rs*gv.w+bv.w);
  ((ushort4*)(h+(size_t)row*Dd))[tid]=o;
}

// ---------------- fp32 -> bf16 transposing weight prep: out[c][r] = in[r][c] ----
__global__ __launch_bounds__(256) void wT_kernel(const float* __restrict__ in,
    unsigned short* __restrict__ out, int R, int Cc){
  __shared__ float t[32][33];
  int c0 = blockIdx.x*32, r0 = blockIdx.y*32;
  int tx = threadIdx.x&31, ty = threadIdx.x>>5;   // 32 x 8
#pragma unroll
  for (int k=0;k<4;k++)
    t[ty+8*k][tx] = in[(size_t)(r0+ty+8*k)*Cc + c0+tx];
  __syncthreads();
#pragma unroll
  for (int k=0;k<4;k++)
    out[(size_t)(c0+ty+8*k)*R + r0+tx] = f2bf(t[tx][ty+8*k]);
}

// ---------------- bf16 V transpose: vT[b][d][k] = kvb[b][k][Dd+d] ----------------
__global__ __launch_bounds__(256) void vT_kernel(const unsigned short* __restrict__ kvb,
    unsigned short* __restrict__ vT){
  __shared__ unsigned short t[32][33];
  int b = blockIdx.z;
  int d0 = blockIdx.x*32, k0 = blockIdx.y*32;
  const unsigned short* in = kvb + (size_t)b*Nn*KVW + Dd;
  unsigned short* out = vT + (size_t)b*Dd*Nn;
  int tx = threadIdx.x&31, ty = threadIdx.x>>5;
#pragma unroll
  for (int k=0;k<4;k++)
    t[ty+8*k][tx] = in[(size_t)(k0+ty+8*k)*KVW + d0+tx];
  __syncthreads();
#pragma unroll
  for (int k=0;k<4;k++)
    out[(size_t)(d0+ty+8*k)*Nn + k0+tx] = t[tx][ty+8*k];
}

// ---------------- zero the l-sums (ws is poisoned each call) ----------------
__global__ __launch_bounds__(256) void zero_kernel(float* __restrict__ p){
  ((float4*)p)[blockIdx.x*256 + threadIdx.x] = float4{0.f,0.f,0.f,0.f};
}

// ---------------- Generic batched bf16 MFMA GEMM: C = A @ Bt^T ----------------
// BM=128 x BN x BK=32, 4 waves, padded RS=40 rows, reg prefetch. (proven r4-r6)
template <int BN, typename CT>
__global__ __launch_bounds__(256) void mgemm(
    const unsigned short* __restrict__ A, const unsigned short* __restrict__ Bt,
    CT* __restrict__ C, int K, int lda, int ldb, int ldc,
    long sAz, long sBz, long sCz, int accum){
  constexpr int BM = 128, BK = 32;
  constexpr int RS = 40;
  constexpr int WC = (BN==128)?2:1;
  constexpr int WR = 4/WC;
  constexpr int FM = BM/(WR*16);
  constexpr int FN = BN/(WC*16);
  __shared__ __align__(16) short As[BM*RS];
  __shared__ __align__(16) short Bs[BN*RS];
  int tid = threadIdx.x;
  long z = blockIdx.z;
  const unsigned short* Ab = A + z*sAz + (size_t)blockIdx.y*BM*lda;
  const unsigned short* Bb = Bt + z*sBz + (size_t)blockIdx.x*BN*ldb;
  CT* Cb = C + z*sCz + (size_t)blockIdx.y*BM*ldc + (size_t)blockIdx.x*BN;
  int wid = tid>>6, lane = tid&63;
  int wr = (WC==2)?(wid>>1):wid;
  int wc = (WC==2)?(wid&1):0;
  int r0 = tid>>2, s0 = tid&3;
  f32x4 acc[FM][FN] = {};
  int nk = K/BK;
  uint4 a0, a1, b0, b1;
  a0 = *(const uint4*)(Ab + (size_t)r0*lda + s0*8);
  a1 = *(const uint4*)(Ab + (size_t)(r0+64)*lda + s0*8);
  b0 = *(const uint4*)(Bb + (size_t)r0*ldb + s0*8);
  if constexpr (BN==128) b1 = *(const uint4*)(Bb + (size_t)(r0+64)*ldb + s0*8);
  *(uint4*)&As[r0*RS + s0*8]      = a0;
  *(uint4*)&As[(r0+64)*RS + s0*8] = a1;
  *(uint4*)&Bs[r0*RS + s0*8]      = b0;
  if constexpr (BN==128) *(uint4*)&Bs[(r0+64)*RS + s0*8] = b1;
  __syncthreads();
  for (int t=0; t<nk; t++){
    if (t+1 < nk){
      int k0 = (t+1)*BK;
      a0 = *(const uint4*)(Ab + (size_t)r0*lda + k0 + s0*8);
      a1 = *(const uint4*)(Ab + (size_t)(r0+64)*lda + k0 + s0*8);
      b0 = *(const uint4*)(Bb + (size_t)r0*ldb + k0 + s0*8);
      if constexpr (BN==128) b1 = *(const uint4*)(Bb + (size_t)(r0+64)*ldb + k0 + s0*8);
    }
    bf16x8 af[FM], bfr[FN];
#pragma unroll
    for (int m=0;m<FM;m++){
      int row = wr*(FM*16) + m*16 + (lane&15);
      af[m] = *(const bf16x8*)&As[row*RS + (lane>>4)*8];
    }
#pragma unroll
    for (int n=0;n<FN;n++){
      int col = wc*(FN*16) + n*16 + (lane&15);
      bfr[n] = *(const bf16x8*)&Bs[col*RS + (lane>>4)*8];
    }
#pragma unroll
    for (int m=0;m<FM;m++)
#pragma unroll
      for (int n=0;n<FN;n++)
        acc[m][n] = __builtin_amdgcn_mfma_f32_16x16x32_bf16(af[m], bfr[n], acc[m][n], 0, 0, 0);
    if (t+1 < nk){
      __syncthreads();
      *(uint4*)&As[r0*RS + s0*8]      = a0;
      *(uint4*)&As[(r0+64)*RS + s0*8] = a1;
      *(uint4*)&Bs[r0*RS + s0*8]      = b0;
      if constexpr (BN==128) *(uint4*)&Bs[(r0+64)*RS + s0*8] = b1;
      __syncthreads();
    }
  }
#pragma unroll
  for (int m=0;m<FM;m++){
    int row = wr*(FM*16) + m*16 + (lane>>4)*4;
#pragma unroll
    for (int n=0;n<FN;n++){
      int col = wc*(FN*16) + n*16 + (lane&15);
#pragma unroll
      for (int rg=0;rg<4;rg++)
        storeC(Cb + (size_t)(row+rg)*ldc + col, acc[m][n][rg], accum);
    }
  }
}

// ------ statsl: QK^T + exp + row-sum atomics ONLY (no U write). z = b*16+h. ----
__global__ __launch_bounds__(256) void statsl_kernel(
    const unsigned short* __restrict__ kvb,   // [Bb][Nn][KVW]
    float* __restrict__ lsum){                // [Bb*Hh][Nn], pre-zeroed
  constexpr int BK = 32, RS = 40;
  constexpr int FM = 4, FN = 4;
  __shared__ __align__(16) short As[128*RS];
  __shared__ __align__(16) short Bs[128*RS];
  int tid = threadIdx.x;
  int z = blockIdx.z;                         // b*16 + h
  const unsigned short* base = kvb + (size_t)(z>>4)*Nn*KVW + (z&15)*HD;
  const unsigned short* Ab = base + (size_t)blockIdx.y*128*KVW;
  const unsigned short* Bq = base + (size_t)blockIdx.x*128*KVW;
  float* lrow = lsum + (size_t)z*Nn + blockIdx.y*128;
  int wid = tid>>6, lane = tid&63;
  int wr = wid>>1, wc = wid&1;
  int r0 = tid>>2, s0 = tid&3;
  f32x4 acc[FM][FN] = {};
  uint4 a0, a1, b0, b1;
  a0 = *(const uint4*)(Ab + (size_t)r0*KVW + s0*8);
  a1 = *(const uint4*)(Ab + (size_t)(r0+64)*KVW + s0*8);
  b0 = *(const uint4*)(Bq + (size_t)r0*KVW + s0*8);
  b1 = *(const uint4*)(Bq + (size_t)(r0+64)*KVW + s0*8);
  *(uint4*)&As[r0*RS + s0*8]      = a0;
  *(uint4*)&As[(r0+64)*RS + s0*8] = a1;
  *(uint4*)&Bs[r0*RS + s0*8]      = b0;
  *(uint4*)&Bs[(r0+64)*RS + s0*8] = b1;
  __syncthreads();
  for (int t=0; t<HD/BK; t++){
    if (t == 0){
      a0 = *(const uint4*)(Ab + (size_t)r0*KVW + BK + s0*8);
      a1 = *(const uint4*)(Ab + (size_t)(r0+64)*KVW + BK + s0*8);
      b0 = *(const uint4*)(Bq + (size_t)r0*KVW + BK + s0*8);
      b1 = *(const uint4*)(Bq + (size_t)(r0+64)*KVW + BK + s0*8);
    }
    bf16x8 af[FM], bfr[FN];
#pragma unroll
    for (int m=0;m<FM;m++)
      af[m] = *(const bf16x8*)&As[(wr*64 + m*16 + (lane&15))*RS + (lane>>4)*8];
#pragma unroll
    for (int n=0;n<FN;n++)
      bfr[n] = *(const bf16x8*)&Bs[(wc*64 + n*16 + (lane&15))*RS + (lane>>4)*8];
#pragma unroll
    for (int m=0;m<FM;m++)
#pragma unroll
      for (int n=0;n<FN;n++)
        acc[m][n] = __builtin_amdgcn_mfma_f32_16x16x32_bf16(af[m], bfr[n], acc[m][n], 0, 0, 0);
    if (t == 0){
      __syncthreads();
      *(uint4*)&As[r0*RS + s0*8]      = a0;
      *(uint4*)&As[(r0+64)*RS + s0*8] = a1;
      *(uint4*)&Bs[r0*RS + s0*8]      = b0;
      *(uint4*)&Bs[(r0+64)*RS + s0*8] = b1;
      __syncthreads();
    }
  }
  float part[FM][4];
#pragma unroll
  for (int m=0;m<FM;m++)
#pragma unroll
    for (int rg=0;rg<4;rg++) part[m][rg] = 0.f;
#pragma unroll
  for (int m=0;m<FM;m++)
#pragma unroll
    for (int n=0;n<FN;n++)
#pragma unroll
      for (int rg=0;rg<4;rg++)
        part[m][rg] += __expf(acc[m][n][rg] - SHIFT);
#pragma unroll
  for (int m=0;m<FM;m++)
#pragma unroll
    for (int rg=0;rg<4;rg++){
      float s = part[m][rg];
#pragma unroll
      for (int off=1; off<16; off<<=1) s += __shfl_xor(s, off);
      if ((lane&15)==0)
        atomicAdd(&lrow[wr*64 + m*16 + (lane>>4)*4 + rg], s);
    }
}

// ------ mixexp: PM[g][q][k] = bf16( sum_h Wx[g,h] * exp(S_h(q,k)-SHIFT) / l_h(q) )
// Fused QK^T-recompute + softmax-normalize + head-mix; U never materialized.
// Tile q=16, k=64; 4 waves own 16 k-cols each; h-loop with reg prefetch.
__global__ __launch_bounds__(256) void mixexp_kernel(
    const unsigned short* __restrict__ kvb_b,  // [Nn][KVW] (batch base)
    const float* __restrict__ Wx,
    const float* __restrict__ lsum_b,          // [Hh][Nn] (batch base)
    unsigned short* __restrict__ PM){          // [16 g][Nn][Nn]
  constexpr int QS = 72;   // padded row stride (shorts), 144B = 16B-aligned rows
  __shared__ __align__(16) short Qs[16*QS];
  __shared__ __align__(16) short Ks[64*QS];
  __shared__ float Wl[256];
  __shared__ float rls[16][16];                // [h][q-row]
  int tid = threadIdx.x;
  int k0 = blockIdx.x*64, q0 = blockIdx.y*16;
  int wv = tid>>6, lane = tid&63;
  Wl[tid] = Wx[tid];
  {
    int h = tid>>4, r = tid&15;
    rls[h][r] = 1.f/lsum_b[(size_t)h*Nn + q0 + r];
  }
  // staging coords: Q 16x64 (8B/thread), K 64x64 (32B/thread)
  int qr = tid>>4, qc = (tid&15)*4;
  int kr = tid>>2, kc = (tid&3)*16;
  const unsigned short* Qg = kvb_b + (size_t)(q0+qr)*KVW + qc;
  const unsigned short* Kg = kvb_b + (size_t)(k0+kr)*KVW + kc;
  uint2 qv; uint4 kv0, kv1;
  qv  = *(const uint2*)(Qg);
  kv0 = *(const uint4*)(Kg);
  kv1 = *(const uint4*)(Kg + 8);
  *(uint2*)&Qs[qr*QS + qc]     = qv;
  *(uint4*)&Ks[kr*QS + kc]     = kv0;
  *(uint4*)&Ks[kr*QS + kc + 8] = kv1;
  __syncthreads();
  float pmacc[16][4] = {};
  for (int h=0; h<16; h++){
    if (h+1 < 16){
      qv  = *(const uint2*)(Qg + (h+1)*64);
      kv0 = *(const uint4*)(Kg + (h+1)*64);
      kv1 = *(const uint4*)(Kg + (h+1)*64 + 8);
    }
    bf16x8 af0 = *(const bf16x8*)&Qs[(lane&15)*QS + (lane>>4)*8];
    bf16x8 af1 = *(const bf16x8*)&Qs[(lane&15)*QS + (lane>>4)*8 + 32];
    bf16x8 bf0 = *(const bf16x8*)&Ks[(wv*16+(lane&15))*QS + (lane>>4)*8];
    bf16x8 bf1 = *(const bf16x8*)&Ks[(wv*16+(lane&15))*QS + (lane>>4)*8 + 32];
    f32x4 acc = {};
    acc = __builtin_amdgcn_mfma_f32_16x16x32_bf16(af0, bf0, acc, 0, 0, 0);
    acc = __builtin_amdgcn_mfma_f32_16x16x32_bf16(af1, bf1, acc, 0, 0, 0);
    float er[4];
#pragma unroll
    for (int rg=0; rg<4; rg++)
      er[rg] = __expf(acc[rg] - SHIFT) * rls[h][(lane>>4)*4 + rg];
#pragma unroll
    for (int g=0; g<16; g++){
      float w = Wl[g*16 + h];
#pragma unroll
      for (int rg=0; rg<4; rg++) pmacc[g][rg] += w*er[rg];
    }
    if (h+1 < 16){
      __syncthreads();
      *(uint2*)&Qs[qr*QS + qc]     = qv;
      *(uint4*)&Ks[kr*QS + kc]     = kv0;
      *(uint4*)&Ks[kr*QS + kc + 8] = kv1;
      __syncthreads();
    }
  }
  int col = k0 + wv*16 + (lane&15);
#pragma unroll
  for (int g=0; g<16; g++){
    unsigned short* Pg = PM + ((size_t)g*Nn + q0)*Nn + col;
#pragma unroll
    for (int rg=0; rg<4; rg++){
      int row = (lane>>4)*4 + rg;
      Pg[(size_t)row*Nn] = f2bf(pmacc[g][rg]);
    }
  }
}

extern "C" void kernel_launch(void* const* d_in, const int* in_sizes, int n_in,
                              void* d_out, int out_size, void* d_ws, size_t ws_size,
                              hipStream_t stream){
  (void)in_sizes; (void)n_in; (void)out_size; (void)ws_size;
  const float* x    = (const float*)d_in[0];
  const float* lng  = (const float*)d_in[1];
  const float* lnb  = (const float*)d_in[2];
  const float* Wkv  = (const float*)d_in[3];
  const float* Wx   = (const float*)d_in[4];
  // d_in[5] = W_xa: dead code in reference (its output _o2 is discarded)
  const float* Wout = (const float*)d_in[6];
  float* out = (float*)d_out;

  char* p = (char*)d_ws;
  unsigned short* h_b   = (unsigned short*)p; p += (size_t)Bb*Nn*Dd*2;   // 8 MB
  unsigned short* kvb   = (unsigned short*)p; p += (size_t)Bb*Nn*KVW*2;  // 16 MB
  unsigned short* WkvT  = (unsigned short*)p; p += (size_t)KVW*Dd*2;     // 4 MB
  unsigned short* WoutT = (unsigned short*)p; p += (size_t)Dd*Dd*2;      // 2 MB
  unsigned short* vTb   = (unsigned short*)p; p += (size_t)Bb*Dd*Nn*2;   // 8 MB
  unsigned short* o1b   = (unsigned short*)p; p += (size_t)Bb*Nn*Dd*2;   // 8 MB
  float*          lb    = (float*)p;          p += (size_t)Bb*Hh*Nn*4;   // 256 KB
  unsigned short* PM    = (unsigned short*)p;                            // 134 MB

  // weight prep + LN + projections
  wT_kernel<<<dim3(KVW/32, Dd/32), 256, 0, stream>>>(Wkv, WkvT, Dd, KVW);
  wT_kernel<<<dim3(Dd/32, Dd/32), 256, 0, stream>>>(Wout, WoutT, Dd, Dd);
  ln_kernel<<<Bb*Nn, 256, 0, stream>>>(x, lng, lnb, h_b);
  mgemm<128, unsigned short><<<dim3(KVW/128, (Bb*Nn)/128, 1), 256, 0, stream>>>(
      h_b, WkvT, kvb, Dd, Dd, Dd, KVW, 0, 0, 0, 0);
  vT_kernel<<<dim3(Dd/32, Nn/32, Bb), 256, 0, stream>>>(kvb, vTb);
  zero_kernel<<<(Bb*Hh*Nn)/1024, 256, 0, stream>>>(lb);

  // softmax denominators for both batches (no U write)
  statsl_kernel<<<dim3(Nn/128, Nn/128, Bb*Hh), 256, 0, stream>>>(kvb, lb);

  for (int b=0;b<Bb;b++){
    const unsigned short* kvb_b = kvb + (size_t)b*Nn*KVW;
    const float* lb_b = lb + (size_t)b*Hh*Nn;
    // PM[g][q][k] directly (QK^T recompute fused with exp+mix; no U tensor)
    mixexp_kernel<<<dim3(Nn/64, Nn/16), 256, 0, stream>>>(kvb_b, Wx, lb_b, PM);
    // o1[q][g*64+d] = PM_g @ V_g  (full K, bf16 out)
    mgemm<64, unsigned short><<<dim3(1, Nn/128, Hh), 256, 0, stream>>>(
        PM, vTb + (size_t)b*Dd*Nn, o1b + (size_t)b*Nn*Dd,
        Nn, Nn, Nn, Dd, (long)Nn*Nn, (long)64*Nn, 64, 0);
  }
  // out = o1 @ W_out (fp32 out)
  mgemm<128, float><<<dim3(Dd/128, (Bb*Nn)/128, 1), 256, 0, stream>>>(
      o1b, WoutT, out, Dd, Dd, Dd, Dd, 0, 0, 0, 0);
}